// Round 6
// baseline (6275.626 us; speedup 1.0000x reference)
//
#include <hip/hip_runtime.h>
#include <cstdint>
#include <cstddef>

typedef __attribute__((ext_vector_type(8))) short short8;
typedef __attribute__((ext_vector_type(4))) float floatx4;

constexpr int kSeq = 512;
constexpr int kBatch = 256;
constexpr int kIn = 15;
constexpr int kH = 512;
constexpr int kG = 4 * kH;                      // 2048 gate cols, order i,f,g,o
constexpr int kRing = 17;                       // ring depth (> window 16)
constexpr size_t kHSlot = (size_t)kBatch * kH;  // elements per h slot
// LDS: 128 KB weights (fragment-linear) + 4 waves * 768 B transpose scratch
constexpr size_t kShmemBytes = 131072 + 4096;

__device__ __forceinline__ unsigned short f2bf(float f) {
    union { float f; unsigned u; } v; v.f = f;
    unsigned u = v.u;
    return (unsigned short)((u + 0x7fffu + ((u >> 16) & 1u)) >> 16);
}

__device__ __forceinline__ float sigm(float x) { return 1.0f / (1.0f + __expf(-x)); }
__device__ __forceinline__ float tanh_(float x) { return 1.0f - 2.0f / (1.0f + __expf(2.0f * x)); }

// 16-B write-through store (LLC always current; h never dirty in any L2)
#define LLC_STORE16(P, V)                                                     \
    asm volatile("global_store_dwordx4 %0, %1, off sc0 sc1"                   \
                 :: "v"(P), "v"(V) : "memory")

// Strided flag wait (boundary rendezvous only): lanes 0..31 watch one 64B
// line each; bounded busy-spin degrades to s_sleep past ~4096 iters.
__device__ __forceinline__ void waitf(const int* flags, int tgt, int lane, int& fc) {
    if (tgt <= 0) return;
    bool watch = (lane < 32);
    if (__all(!watch || fc >= tgt)) return;
    int spin = 0;
    for (;;) {
        if (watch && fc < tgt)
            fc = __hip_atomic_load(flags + lane * 16,
                                   __ATOMIC_RELAXED, __HIP_MEMORY_SCOPE_AGENT);
        if (__all(!watch || fc >= tgt)) return;
        if (++spin > 4096) __builtin_amdgcn_s_sleep(8);
    }
}

// ---- data-embedded signaling (poison polling) ----
// Ring slots are pre-poisoned with bf16 0xFFFF (NaN - unreachable: h is a
// finite real in (-1,1), f2bf never yields 0xFFFF). Consumers poll their 16B
// chunks with sc0sc1 (LLC-coherent, cache-bypassing) loads until both end
// elements are non-poison. The producer's 16B sc0sc1 store IS the signal:
// no drain, no flag, no barrier on the per-step path.
__device__ __forceinline__ void issue16(short8* a, const unsigned short* hp, unsigned mask) {
#pragma unroll
    for (int kk = 0; kk < 16; ++kk)
        if (mask & (1u << kk))
            asm volatile("global_load_dwordx4 %0, %1, off sc0 sc1"
                         : "=v"(a[kk]) : "v"(hp + (size_t)kk * 32) : "memory");
}

__device__ __forceinline__ void chunk_wait() {
    asm volatile("s_waitcnt vmcnt(0)" ::: "memory");
    __builtin_amdgcn_sched_barrier(0);   // rule #18: stop MFMA hoisting past the wait
}

__device__ __forceinline__ unsigned stale_of(const short8* a, unsigned mask) {
    unsigned st = 0;
#pragma unroll
    for (int kk = 0; kk < 16; ++kk)
        if (mask & (1u << kk))
            if (a[kk][0] == (short)-1 || a[kk][7] == (short)-1) st |= (1u << kk);
    return st;
}

__device__ __forceinline__ void repoll(short8* a, const unsigned short* hp, unsigned stale) {
    int spin = 0;
    while (__any(stale != 0)) {
        issue16(a, hp, stale);
        chunk_wait();
        stale = stale_of(a, stale);
        if (++spin > 2048) __builtin_amdgcn_s_sleep(8);
    }
}

// Window-boundary rendezvous (every 16 steps). Two phases:
//  1) wf=B: "my reads for steps <B are done" - wait all 64 blocks' wf>=B.
//  2) poison my own output region for slots [B,B+16) (their data, steps
//     B-17..B-2, was last read at step <=B-1, covered by phase 1), drain,
//     pf=B, wait all pf>=B. No consumer polls a window-B slot before this
//     returns, so stale-real-data can never be mistaken for fresh.
__device__ __forceinline__ void boundary(
    int B, unsigned short* ring, int g, int j0, int tid, int lane,
    int* wfs, int* pfs, int* my_wf, int* my_pf,
    int& cw1, int& cw2, int& cp1, int& cp2)
{
    __syncthreads();
    if (tid == 0) __hip_atomic_store(my_wf, B, __ATOMIC_RELAXED, __HIP_MEMORY_SCOPE_AGENT);
    waitf(wfs, B, lane, cw1);
    waitf(wfs + 512, B, lane, cw2);
    short8 pv;
#pragma unroll
    for (int j = 0; j < 8; ++j) pv[j] = (short)-1;
    // 16 slots x 64 rows x 2 segs = 2048 chunks over 256 threads
#pragma unroll
    for (int i = 0; i < 8; ++i) {
        int c = tid * 8 + i;
        int t = c >> 7, r = (c >> 1) & 63, seg = c & 1;
        unsigned short* p = ring + (size_t)((B + t) % kRing) * kHSlot
                            + (size_t)((g << 6) + r) * kH + j0 + seg * 8;
        LLC_STORE16(p, pv);
    }
    __builtin_amdgcn_s_waitcnt(0);
    __syncthreads();
    if (tid == 0) __hip_atomic_store(my_pf, B, __ATOMIC_RELAXED, __HIP_MEMORY_SCOPE_AGENT);
    waitf(pfs, B, lane, cp1);
    waitf(pfs + 512, B, lane, cp2);
}

__global__ void k_conv(const float* __restrict__ src, unsigned short* __restrict__ dst, int n) {
    int i = blockIdx.x * blockDim.x + threadIdx.x;
    if (i < n) dst[i] = f2bf(src[i]);
}

__global__ void k_conv_pad(const float* __restrict__ src, unsigned short* __restrict__ dst, int rows) {
    int i = blockIdx.x * blockDim.x + threadIdx.x;
    if (i >= rows * 32) return;
    int r = i >> 5, k = i & 31;
    dst[i] = (k < kIn) ? f2bf(src[r * kIn + k]) : (unsigned short)0;
}

// Persistent kernel. group g = blockIdx&3 (64 batch rows); role = blockIdx>>2:
// 0..31 layer-1, 32..63 layer-2 (16 h-cols each). h1/h2: 17-slot rings,
// poison-initialized (slot 16 = zeros = h[-1] state). Steady-state steps have
// NO barriers, NO flags, NO drains: producers store sc0sc1; consumers poll
// the data chunks directly. Flags exist only at 16-step boundaries.
__global__ __launch_bounds__(256) void k_persist(
    const unsigned short* __restrict__ whh1b,
    const unsigned short* __restrict__ wih1b,
    const unsigned short* __restrict__ wih2b,
    const unsigned short* __restrict__ whh2b,
    const unsigned short* __restrict__ xb,
    const float* __restrict__ bih1, const float* __restrict__ bhh1,
    const float* __restrict__ bih2, const float* __restrict__ bhh2,
    unsigned short* __restrict__ h1r,   // kRing slots of kBatch*kH
    unsigned short* __restrict__ h2r,   // kRing slots of kBatch*kH
    float* __restrict__ h2f,
    int* __restrict__ flags)            // per group 2048 ints: wf1@0 wf2@512 pf1@1024 pf2@1536 (stride-16)
{
    extern __shared__ unsigned short lw[];
    const int bid = blockIdx.x;
    const int g = bid & 3;
    const int role = bid >> 2;
    const bool is2 = role >= 32;
    const int rid = role & 31;
    const int j0 = rid << 4;
    const int tid = (int)threadIdx.x;
    const int wave = tid >> 6;
    const int lane = tid & 63;
    const int lcol = lane & 15;
    const int quad = lane >> 4;
    const int m0 = (g << 6) + wave * 16;
    const int arow = m0 + lcol;
    const int koff = quad * 8;

    int* fg = flags + g * 2048;
    int* my_wf = fg + (is2 ? 512 : 0) + rid * 16;
    int* my_pf = my_wf + 1024;
    unsigned short* scr = lw + 65536 + wave * 384;   // 16 rows x stride-24 elems

    // ---- stage weight slices into LDS, fragment-linear layout ----
    if (!is2) {
        for (int i = tid; i < 4096; i += 256) {
            int ln = i >> 6, gg = ln >> 4, u = ln & 15;
            int c = i & 63, kk = c >> 2, qd = c & 3;
            *(short8*)&lw[((gg * 16 + kk) << 9) + ((qd * 16 + u) << 3)] =
                *(const short8*)&whh1b[(size_t)((gg << 9) + j0 + u) * kH + c * 8];
        }
        for (int i = tid; i < 256; i += 256) {
            int ln = i >> 2, gg = ln >> 4, u = ln & 15;
            int qd = i & 3;
            *(short8*)&lw[((64 + gg) << 9) + ((qd * 16 + u) << 3)] =
                *(const short8*)&wih1b[((gg << 9) + j0 + u) * 32 + qd * 8];
        }
    } else {
        for (int i = tid; i < 4096; i += 256) {
            int ln = i >> 6, gg = ln >> 4, u = ln & 15;
            int c = i & 63, kk = c >> 2, qd = c & 3;
            int dst = ((gg * 16 + kk) << 9) + ((qd * 16 + u) << 3);
            size_t src = (size_t)((gg << 9) + j0 + u) * kH + c * 8;
            *(short8*)&lw[dst] = *(const short8*)&wih2b[src];
            *(short8*)&lw[dst + (64 << 9)] = *(const short8*)&whh2b[src];
        }
    }
    float bsum[4];
#pragma unroll
    for (int gg = 0; gg < 4; ++gg) {
        int n = (gg << 9) + j0 + lcol;
        bsum[gg] = is2 ? (bih2[n] + bhh2[n]) : (bih1[n] + bhh1[n]);
    }
    __syncthreads();

    float creg[4] = {0.f, 0.f, 0.f, 0.f};
    int cw1 = 0, cw2 = 0, cp1 = 0, cp2 = 0;   // boundary flag caches

    if (!is2) {
        for (int s = 0; s < kSeq; ++s) {
            if (s && !(s & 15))
                boundary(s, h1r, g, j0, tid, lane, fg, fg + 1024, my_wf, my_pf,
                         cw1, cw2, cp1, cp2);
            floatx4 acc[4];
#pragma unroll
            for (int gg = 0; gg < 4; ++gg)
                acc[gg] = (floatx4){bsum[gg], bsum[gg], bsum[gg], bsum[gg]};

            // issue h1[s-1] poll; its latency hides under the x-GEMM
            const unsigned short* hp = h1r + (size_t)((s + 16) % kRing) * kHSlot
                                       + (size_t)arow * kH + koff;
            short8 a[16];
            issue16(a, hp, 0xFFFFu);

            short8 ax = *(const short8*)(xb + ((size_t)s * kBatch + arow) * 32 + koff);
#pragma unroll
            for (int gg = 0; gg < 4; ++gg) {
                short8 b = *(const short8*)&lw[((64 + gg) << 9) + (lane << 3)];
                acc[gg] = __builtin_amdgcn_mfma_f32_16x16x32_bf16(ax, b, acc[gg], 0, 0, 0);
            }
            chunk_wait();
            if (s > 0) repoll(a, hp, stale_of(a, 0xFFFFu));  // s==0: slot16 zeros, no check

#pragma unroll
            for (int kk = 0; kk < 16; ++kk) {
#pragma unroll
                for (int gg = 0; gg < 4; ++gg) {
                    short8 b = *(const short8*)&lw[((gg * 16 + kk) << 9) + (lane << 3)];
                    acc[gg] = __builtin_amdgcn_mfma_f32_16x16x32_bf16(a[kk], b, acc[gg], 0, 0, 0);
                }
            }

            // epilogue: activations -> per-wave LDS transpose -> 16B WT stores
            unsigned short* hw = h1r + (size_t)(s % kRing) * kHSlot;
#pragma unroll
            for (int r = 0; r < 4; ++r) {
                int row = quad * 4 + r;
                float gi = acc[0][r], gf = acc[1][r], ggv = acc[2][r], go = acc[3][r];
                float cn = sigm(gf) * creg[r] + sigm(gi) * tanh_(ggv);
                float hn = sigm(go) * tanh_(cn);
                creg[r] = cn;
                scr[row * 24 + lcol] = f2bf(hn);
            }
            if (lane < 32) {
                int row = lane >> 1, seg = lane & 1;
                short8 v = *(short8*)&scr[row * 24 + seg * 8];
                unsigned short* gp = hw + (size_t)(m0 + row) * kH + j0 + seg * 8;
                LLC_STORE16(gp, v);
            }
            // no drain, no barrier, no flag: the stores are the signal
        }
    } else {
        for (int u = 0; u < kSeq; ++u) {
            if (u && !(u & 15))
                boundary(u, h2r, g, j0, tid, lane, fg, fg + 1024, my_wf, my_pf,
                         cw1, cw2, cp1, cp2);
            floatx4 acc[4];
#pragma unroll
            for (int gg = 0; gg < 4; ++gg)
                acc[gg] = (floatx4){bsum[gg], bsum[gg], bsum[gg], bsum[gg]};

            // poll h2[u-1] (ready early: peers wrote it last step)
            const unsigned short* hp2 = h2r + (size_t)((u + 16) % kRing) * kHSlot
                                        + (size_t)arow * kH + koff;
            short8 a2[16];
            issue16(a2, hp2, 0xFFFFu);
            chunk_wait();
            if (u > 0) repoll(a2, hp2, stale_of(a2, 0xFFFFu));  // u==0: slot16 zeros

            // issue h1[u] poll now; latency hides under the h2-GEMM
            const unsigned short* hp1 = h1r + (size_t)(u % kRing) * kHSlot
                                        + (size_t)arow * kH + koff;
            short8 a1[16];
            issue16(a1, hp1, 0xFFFFu);

#pragma unroll
            for (int kk = 0; kk < 16; ++kk) {
#pragma unroll
                for (int gg = 0; gg < 4; ++gg) {
                    short8 b = *(const short8*)&lw[((64 + gg * 16 + kk) << 9) + (lane << 3)];
                    acc[gg] = __builtin_amdgcn_mfma_f32_16x16x32_bf16(a2[kk], b, acc[gg], 0, 0, 0);
                }
            }
            chunk_wait();
            repoll(a1, hp1, stale_of(a1, 0xFFFFu));   // always checked (L1 writes it this step)

#pragma unroll
            for (int kk = 0; kk < 16; ++kk) {
#pragma unroll
                for (int gg = 0; gg < 4; ++gg) {
                    short8 b = *(const short8*)&lw[((gg * 16 + kk) << 9) + (lane << 3)];
                    acc[gg] = __builtin_amdgcn_mfma_f32_16x16x32_bf16(a1[kk], b, acc[gg], 0, 0, 0);
                }
            }

            unsigned short* hw = h2r + (size_t)(u % kRing) * kHSlot;
            const int j = j0 + lcol;
#pragma unroll
            for (int r = 0; r < 4; ++r) {
                int row = quad * 4 + r;
                float gi = acc[0][r], gf = acc[1][r], ggv = acc[2][r], go = acc[3][r];
                float cn = sigm(gf) * creg[r] + sigm(gi) * tanh_(ggv);
                float hn = sigm(go) * tanh_(cn);
                creg[r] = cn;
                scr[row * 24 + lcol] = f2bf(hn);
                if (u == kSeq - 1) h2f[(size_t)(m0 + row) * kH + j] = hn;
            }
            if (lane < 32) {
                int row = lane >> 1, seg = lane & 1;
                short8 v = *(short8*)&scr[row * 24 + seg * 8];
                unsigned short* gp = hw + (size_t)(m0 + row) * kH + j0 + seg * 8;
                LLC_STORE16(gp, v);
            }
            // no drain, no barrier, no flag
        }
    }
}

__global__ __launch_bounds__(64) void k_head(
    const float* __restrict__ h2f, const float* __restrict__ fc1w,
    const float* __restrict__ fc1b, const float* __restrict__ fcw,
    const float* __restrict__ fcb, float* __restrict__ out)
{
    int m = blockIdx.x;
    int j = threadIdx.x;
    const float* hr = h2f + (size_t)m * kH;
    const float* wr = fc1w + (size_t)j * kH;
    float sacc = 0.f;
    for (int k = 0; k < kH; ++k) sacc += fmaxf(hr[k], 0.f) * wr[k];
    float rv = fmaxf(sacc + fc1b[j], 0.f) * fcw[j];
#pragma unroll
    for (int off = 32; off >= 1; off >>= 1) rv += __shfl_down(rv, off);
    if (j == 0) out[m] = 2.0f * (rv + fcb[0]);
}

extern "C" void kernel_launch(void* const* d_in, const int* in_sizes, int n_in,
                              void* d_out, int out_size, void* d_ws, size_t ws_size,
                              hipStream_t stream) {
    const float* x    = (const float*)d_in[0];
    const float* Wih1 = (const float*)d_in[1];
    const float* Whh1 = (const float*)d_in[2];
    const float* bih1 = (const float*)d_in[3];
    const float* bhh1 = (const float*)d_in[4];
    const float* Wih2 = (const float*)d_in[5];
    const float* Whh2 = (const float*)d_in[6];
    const float* bih2 = (const float*)d_in[7];
    const float* bhh2 = (const float*)d_in[8];
    const float* fc1w = (const float*)d_in[9];
    const float* fc1b = (const float*)d_in[10];
    const float* fcw  = (const float*)d_in[11];
    const float* fcb  = (const float*)d_in[12];
    float* out = (float*)d_out;

    char* p = (char*)d_ws;
    auto take = [&](size_t bytes) -> char* {
        char* r = p;
        p += (bytes + 255) & ~(size_t)255;
        return r;
    };
    unsigned short* whh1b = (unsigned short*)take((size_t)kG * kH * 2);
    unsigned short* wih2b = (unsigned short*)take((size_t)kG * kH * 2);
    unsigned short* whh2b = (unsigned short*)take((size_t)kG * kH * 2);
    unsigned short* wih1b = (unsigned short*)take((size_t)kG * 32 * 2);
    unsigned short* xb    = (unsigned short*)take((size_t)kSeq * kBatch * 32 * 2);
    unsigned short* h1r = (unsigned short*)take((size_t)kRing * kHSlot * 2);
    unsigned short* h2r = (unsigned short*)take((size_t)kRing * kHSlot * 2);
    int* flags = (int*)take(32768);
    float* h2f = (float*)take((size_t)kBatch * kH * 4);

    // rings: poison everywhere except slot 16 (= h[-1] = zeros, read unchecked
    // at step 0; poisoned by the first boundary before its step-16 reuse)
    hipMemsetAsync(h1r, 0xFF, (size_t)kRing * kHSlot * 2, stream);
    hipMemsetAsync(h2r, 0xFF, (size_t)kRing * kHSlot * 2, stream);
    hipMemsetAsync(h1r + (size_t)16 * kHSlot, 0, kHSlot * 2, stream);
    hipMemsetAsync(h2r + (size_t)16 * kHSlot, 0, kHSlot * 2, stream);
    hipMemsetAsync(flags, 0, 32768, stream);

    int n = kG * kH;
    k_conv<<<(n + 255) / 256, 256, 0, stream>>>(Whh1, whh1b, n);
    k_conv<<<(n + 255) / 256, 256, 0, stream>>>(Wih2, wih2b, n);
    k_conv<<<(n + 255) / 256, 256, 0, stream>>>(Whh2, whh2b, n);
    k_conv_pad<<<(kG * 32 + 255) / 256, 256, 0, stream>>>(Wih1, wih1b, kG);
    k_conv_pad<<<(kSeq * kBatch * 32 + 255) / 256, 256, 0, stream>>>(x, xb, kSeq * kBatch);

    hipFuncSetAttribute((const void*)k_persist,
                        hipFuncAttributeMaxDynamicSharedMemorySize, (int)kShmemBytes);
    void* args[] = {&whh1b, &wih1b, &wih2b, &whh2b, &xb,
                    (void*)&bih1, (void*)&bhh1, (void*)&bih2, (void*)&bhh2,
                    &h1r, &h2r, &h2f, &flags};
    hipError_t e = hipLaunchCooperativeKernel((const void*)k_persist, dim3(256), dim3(256),
                                              args, (unsigned)kShmemBytes, stream);
    if (e != hipSuccess) {
        k_persist<<<256, 256, kShmemBytes, stream>>>(
            whh1b, wih1b, wih2b, whh2b, xb, bih1, bhh1, bih2, bhh2,
            h1r, h2r, h2f, flags);
    }

    k_head<<<kBatch, 64, 0, stream>>>(h2f, fc1w, fc1b, fcw, fcb, out);
}

// Round 7
// 5305.533 us; speedup vs baseline: 1.1828x; 1.1828x over previous
//
#include <hip/hip_runtime.h>
#include <cstdint>
#include <cstddef>

typedef __attribute__((ext_vector_type(8))) short short8;
typedef __attribute__((ext_vector_type(4))) float floatx4;

constexpr int kSeq = 512;
constexpr int kBatch = 256;
constexpr int kIn = 15;
constexpr int kH = 512;
constexpr int kG = 4 * kH;                      // 2048 gate cols, order i,f,g,o
constexpr int kRing = 17;                       // ring depth (> window 16)
constexpr size_t kHSlot = (size_t)kBatch * kH;  // elements per h slot
// LDS: 128 KB weights (fragment-linear) + 4 waves * 768 B transpose scratch + done word
constexpr size_t kShmemBytes = 131072 + 4096;

__device__ __forceinline__ unsigned short f2bf(float f) {
    union { float f; unsigned u; } v; v.f = f;
    unsigned u = v.u;
    return (unsigned short)((u + 0x7fffu + ((u >> 16) & 1u)) >> 16);
}

__device__ __forceinline__ float sigm(float x) { return 1.0f / (1.0f + __expf(-x)); }
__device__ __forceinline__ float tanh_(float x) { return 1.0f - 2.0f / (1.0f + __expf(2.0f * x)); }

// 16-B write-through store (LLC always current; h never dirty in any L2)
#define LLC_STORE16(P, V)                                                     \
    asm volatile("global_store_dwordx4 %0, %1, off sc0 sc1"                   \
                 :: "v"(P), "v"(V) : "memory")

// Wave-aligned flag wait: consumer wave w watches producer wave-w flags only
// (reads are strictly wave-row-aligned). lanes 0..31 watch one 64B line each
// (int [wave] within the line). Bounded busy-spin, s_sleep backoff past 4096.
// Register cache fc exploits monotonicity.
__device__ __forceinline__ void waitf(const int* flags, int tgt, int lane, int& fc) {
    if (tgt <= 0) return;
    bool watch = (lane < 32);
    if (__all(!watch || fc >= tgt)) return;
    int spin = 0;
    for (;;) {
        if (watch && fc < tgt)
            fc = __hip_atomic_load(flags + lane * 16,
                                   __ATOMIC_RELAXED, __HIP_MEMORY_SCOPE_AGENT);
        if (__all(!watch || fc >= tgt)) return;
        if (++spin > 4096) __builtin_amdgcn_s_sleep(8);
    }
}

__global__ void k_conv(const float* __restrict__ src, unsigned short* __restrict__ dst, int n) {
    int i = blockIdx.x * blockDim.x + threadIdx.x;
    if (i < n) dst[i] = f2bf(src[i]);
}

__global__ void k_conv_pad(const float* __restrict__ src, unsigned short* __restrict__ dst, int rows) {
    int i = blockIdx.x * blockDim.x + threadIdx.x;
    if (i >= rows * 32) return;
    int r = i >> 5, k = i & 31;
    dst[i] = (k < kIn) ? f2bf(src[r * kIn + k]) : (unsigned short)0;
}

// Persistent kernel, wave-aligned sync + DVFS heater.
// group g = blockIdx&3 (64 batch rows, 2-XCD-affine); role = blockIdx>>2:
// 0..31 layer-1, 32..63 layer-2 (16 h-cols each). Waves 0..3 compute (wave w
// owns batch rows m0..m0+16); wave 4 is a HEATER: pure v_fmac spin to keep
// the DPM governor from parking SCLK while compute waves sit in latency
// waits (measured effective clock ~0.5-0.7 GHz without it).
//
// Flags are per-(block, wave): f[role][wave] published by wave w after ITS
// s_waitcnt(0) drain — no per-step __syncthreads anywhere (required for the
// heater, and removes the intra-block skew max + barrier hop).
// Consumer wave w polls peers' wave-w flags only (reads are wave-aligned:
// wave w only ever loads rows written by peer wave w).
//
// Window protocol (unchanged): every 16 steps wait f1>=B && f2>=B (per wave)
// + agent acquire fence; ring 17 > window 16 => every ring address re-read
// only across a fence. Producers: sc0sc1 write-through; consumers: plain
// cached loads (L2 absorbs the 16x per-XCD redundancy).
__global__ __launch_bounds__(320) void k_persist(
    const unsigned short* __restrict__ whh1b,
    const unsigned short* __restrict__ wih1b,
    const unsigned short* __restrict__ wih2b,
    const unsigned short* __restrict__ whh2b,
    const unsigned short* __restrict__ xb,
    const float* __restrict__ bih1, const float* __restrict__ bhh1,
    const float* __restrict__ bih2, const float* __restrict__ bhh2,
    unsigned short* __restrict__ h1r,   // kRing slots of kBatch*kH
    unsigned short* __restrict__ h2r,   // kRing slots of kBatch*kH
    float* __restrict__ h2f,
    int* __restrict__ flags)            // per group: f1[32 lines] @ +0, f2 @ +512 ints; int[wave] in line
{
    extern __shared__ unsigned short lw[];
    const int bid = blockIdx.x;
    const int g = bid & 3;
    const int role = bid >> 2;
    const bool is2 = role >= 32;
    const int rid = role & 31;
    const int j0 = rid << 4;
    const int tid = (int)threadIdx.x;
    const int wave = tid >> 6;
    const int lane = tid & 63;
    const int lcol = lane & 15;
    const int quad = lane >> 4;
    const int m0 = (g << 6) + wave * 16;
    const int arow = m0 + lcol;
    const int koff = quad * 8;

    int* f1 = flags + g * 1024;
    int* f2 = f1 + 512;
    int* dn = (int*)(lw + 67072);              // LDS done counter (byte 134144)

    if (wave == 4) {                            // ---- heater wave ----
        __syncthreads();                        // pair with compute staging barrier
        float a0 = 1.0f, a1 = 1.25f, a2 = 1.5f, a3 = 1.75f;
        float m = 1.0f, c = 1e-7f;
        while (__hip_atomic_load(dn, __ATOMIC_RELAXED, __HIP_MEMORY_SCOPE_WORKGROUP) < 4) {
            asm volatile(
                ".rept 16\n\t"
                "v_fmac_f32 %0, %4, %5\n\t"
                "v_fmac_f32 %1, %4, %5\n\t"
                "v_fmac_f32 %2, %4, %5\n\t"
                "v_fmac_f32 %3, %4, %5\n\t"
                ".endr"
                : "+v"(a0), "+v"(a1), "+v"(a2), "+v"(a3)
                : "v"(m), "v"(c));
        }
        return;
    }

    // ---- compute waves (0..3) ----
    int* myflag = (is2 ? f2 : f1) + rid * 16 + wave;
    unsigned short* scr = lw + 65536 + wave * 384;   // 16 rows x stride-24 elems

    if (tid == 0) *dn = 0;

    // stage weight slices into LDS, fragment-linear layout (tid 0..255)
    if (!is2) {
        for (int i = tid; i < 4096; i += 256) {
            int ln = i >> 6, gg = ln >> 4, u = ln & 15;
            int c = i & 63, kk = c >> 2, qd = c & 3;
            *(short8*)&lw[((gg * 16 + kk) << 9) + ((qd * 16 + u) << 3)] =
                *(const short8*)&whh1b[(size_t)((gg << 9) + j0 + u) * kH + c * 8];
        }
        for (int i = tid; i < 256; i += 256) {
            int ln = i >> 2, gg = ln >> 4, u = ln & 15;
            int qd = i & 3;
            *(short8*)&lw[((64 + gg) << 9) + ((qd * 16 + u) << 3)] =
                *(const short8*)&wih1b[((gg << 9) + j0 + u) * 32 + qd * 8];
        }
    } else {
        for (int i = tid; i < 4096; i += 256) {
            int ln = i >> 6, gg = ln >> 4, u = ln & 15;
            int c = i & 63, kk = c >> 2, qd = c & 3;
            int dst = ((gg * 16 + kk) << 9) + ((qd * 16 + u) << 3);
            size_t src = (size_t)((gg << 9) + j0 + u) * kH + c * 8;
            *(short8*)&lw[dst] = *(const short8*)&wih2b[src];
            *(short8*)&lw[dst + (64 << 9)] = *(const short8*)&whh2b[src];
        }
    }
    float bsum[4];
#pragma unroll
    for (int gg = 0; gg < 4; ++gg) {
        int n = (gg << 9) + j0 + lcol;
        bsum[gg] = is2 ? (bih2[n] + bhh2[n]) : (bih1[n] + bhh1[n]);
    }
    __syncthreads();

    float creg[4] = {0.f, 0.f, 0.f, 0.f};
    int fc1 = 0, fc2 = 0;   // per-thread flag caches (wave-w slice)

    if (!is2) {
        for (int s = 0; s < kSeq; ++s) {
            if ((s & 15) == 0) {      // window rendezvous + cache invalidate
                waitf(f1 + wave, s, lane, fc1);
                waitf(f2 + wave, s, lane, fc2);
                __builtin_amdgcn_fence(__ATOMIC_ACQUIRE, "agent");
            }
            floatx4 acc[4];
#pragma unroll
            for (int gg = 0; gg < 4; ++gg)
                acc[gg] = (floatx4){bsum[gg], bsum[gg], bsum[gg], bsum[gg]};

            short8 ax = *(const short8*)(xb + ((size_t)s * kBatch + arow) * 32 + koff);

            waitf(f1 + wave, s, lane, fc1);             // peer wave-w done s-1
            const unsigned short* hp = h1r + (size_t)((s + 16) % kRing) * kHSlot
                                       + (size_t)arow * kH + koff;   // h1[s-1]
            short8 a[16];
#pragma unroll
            for (int kk = 0; kk < 16; ++kk) a[kk] = *(const short8*)(hp + kk * 32);
#pragma unroll
            for (int kk = 0; kk < 16; ++kk) {
#pragma unroll
                for (int gg = 0; gg < 4; ++gg) {
                    short8 b = *(const short8*)&lw[((gg * 16 + kk) << 9) + (lane << 3)];
                    acc[gg] = __builtin_amdgcn_mfma_f32_16x16x32_bf16(a[kk], b, acc[gg], 0, 0, 0);
                }
            }
#pragma unroll
            for (int gg = 0; gg < 4; ++gg) {
                short8 b = *(const short8*)&lw[((64 + gg) << 9) + (lane << 3)];
                acc[gg] = __builtin_amdgcn_mfma_f32_16x16x32_bf16(ax, b, acc[gg], 0, 0, 0);
            }

            // epilogue: activations -> per-wave LDS transpose -> 16B WT stores
            unsigned short* hw = h1r + (size_t)(s % kRing) * kHSlot;
#pragma unroll
            for (int r = 0; r < 4; ++r) {
                int row = quad * 4 + r;
                float gi = acc[0][r], gf = acc[1][r], ggv = acc[2][r], go = acc[3][r];
                float cn = sigm(gf) * creg[r] + sigm(gi) * tanh_(ggv);
                float hn = sigm(go) * tanh_(cn);
                creg[r] = cn;
                scr[row * 24 + lcol] = f2bf(hn);
            }
            if (lane < 32) {
                int row = lane >> 1, seg = lane & 1;
                short8 v = *(short8*)&scr[row * 24 + seg * 8];
                unsigned short* gp = hw + (size_t)(m0 + row) * kH + j0 + seg * 8;
                LLC_STORE16(gp, v);
            }
            __builtin_amdgcn_s_waitcnt(0);              // this wave's stores drained
            if (lane == 0)
                __hip_atomic_store(myflag, s + 1,
                                   __ATOMIC_RELAXED, __HIP_MEMORY_SCOPE_AGENT);
        }
    } else {
        for (int u = 0; u < kSeq; ++u) {
            if ((u & 15) == 0) {      // window rendezvous + cache invalidate
                waitf(f1 + wave, u, lane, fc1);
                waitf(f2 + wave, u, lane, fc2);
                __builtin_amdgcn_fence(__ATOMIC_ACQUIRE, "agent");
            }
            floatx4 acc[4];
#pragma unroll
            for (int gg = 0; gg < 4; ++gg)
                acc[gg] = (floatx4){bsum[gg], bsum[gg], bsum[gg], bsum[gg]};

            waitf(f2 + wave, u, lane, fc2);             // peer wave-w done u-1

            // h2[u-1] GEMM first (hides under L1's tail)
            const unsigned short* hp2 = h2r + (size_t)((u + 16) % kRing) * kHSlot
                                        + (size_t)arow * kH + koff;
            short8 a[16];
#pragma unroll
            for (int kk = 0; kk < 16; ++kk) a[kk] = *(const short8*)(hp2 + kk * 32);
#pragma unroll
            for (int kk = 0; kk < 16; ++kk) {
#pragma unroll
                for (int gg = 0; gg < 4; ++gg) {
                    short8 b = *(const short8*)&lw[((64 + gg * 16 + kk) << 9) + (lane << 3)];
                    acc[gg] = __builtin_amdgcn_mfma_f32_16x16x32_bf16(a[kk], b, acc[gg], 0, 0, 0);
                }
            }

            waitf(f1 + wave, u + 1, lane, fc1);         // L1 wave-w done step u

            const unsigned short* hp1 = h1r + (size_t)(u % kRing) * kHSlot
                                        + (size_t)arow * kH + koff;   // h1[u]
#pragma unroll
            for (int kk = 0; kk < 16; ++kk) a[kk] = *(const short8*)(hp1 + kk * 32);
#pragma unroll
            for (int kk = 0; kk < 16; ++kk) {
#pragma unroll
                for (int gg = 0; gg < 4; ++gg) {
                    short8 b = *(const short8*)&lw[((gg * 16 + kk) << 9) + (lane << 3)];
                    acc[gg] = __builtin_amdgcn_mfma_f32_16x16x32_bf16(a[kk], b, acc[gg], 0, 0, 0);
                }
            }

            unsigned short* hw = h2r + (size_t)(u % kRing) * kHSlot;
            const int j = j0 + lcol;
#pragma unroll
            for (int r = 0; r < 4; ++r) {
                int row = quad * 4 + r;
                float gi = acc[0][r], gf = acc[1][r], ggv = acc[2][r], go = acc[3][r];
                float cn = sigm(gf) * creg[r] + sigm(gi) * tanh_(ggv);
                float hn = sigm(go) * tanh_(cn);
                creg[r] = cn;
                scr[row * 24 + lcol] = f2bf(hn);
                if (u == kSeq - 1) h2f[(size_t)(m0 + row) * kH + j] = hn;
            }
            if (lane < 32) {
                int row = lane >> 1, seg = lane & 1;
                short8 v = *(short8*)&scr[row * 24 + seg * 8];
                unsigned short* gp = hw + (size_t)(m0 + row) * kH + j0 + seg * 8;
                LLC_STORE16(gp, v);
            }
            __builtin_amdgcn_s_waitcnt(0);              // this wave's stores drained
            if (lane == 0)
                __hip_atomic_store(myflag, u + 1,
                                   __ATOMIC_RELAXED, __HIP_MEMORY_SCOPE_AGENT);
        }
    }

    if (lane == 0)
        __hip_atomic_fetch_add(dn, 1, __ATOMIC_RELAXED, __HIP_MEMORY_SCOPE_WORKGROUP);
}

__global__ __launch_bounds__(64) void k_head(
    const float* __restrict__ h2f, const float* __restrict__ fc1w,
    const float* __restrict__ fc1b, const float* __restrict__ fcw,
    const float* __restrict__ fcb, float* __restrict__ out)
{
    int m = blockIdx.x;
    int j = threadIdx.x;
    const float* hr = h2f + (size_t)m * kH;
    const float* wr = fc1w + (size_t)j * kH;
    float sacc = 0.f;
    for (int k = 0; k < kH; ++k) sacc += fmaxf(hr[k], 0.f) * wr[k];
    float rv = fmaxf(sacc + fc1b[j], 0.f) * fcw[j];
#pragma unroll
    for (int off = 32; off >= 1; off >>= 1) rv += __shfl_down(rv, off);
    if (j == 0) out[m] = 2.0f * (rv + fcb[0]);
}

extern "C" void kernel_launch(void* const* d_in, const int* in_sizes, int n_in,
                              void* d_out, int out_size, void* d_ws, size_t ws_size,
                              hipStream_t stream) {
    const float* x    = (const float*)d_in[0];
    const float* Wih1 = (const float*)d_in[1];
    const float* Whh1 = (const float*)d_in[2];
    const float* bih1 = (const float*)d_in[3];
    const float* bhh1 = (const float*)d_in[4];
    const float* Wih2 = (const float*)d_in[5];
    const float* Whh2 = (const float*)d_in[6];
    const float* bih2 = (const float*)d_in[7];
    const float* bhh2 = (const float*)d_in[8];
    const float* fc1w = (const float*)d_in[9];
    const float* fc1b = (const float*)d_in[10];
    const float* fcw  = (const float*)d_in[11];
    const float* fcb  = (const float*)d_in[12];
    float* out = (float*)d_out;

    char* p = (char*)d_ws;
    auto take = [&](size_t bytes) -> char* {
        char* r = p;
        p += (bytes + 255) & ~(size_t)255;
        return r;
    };
    unsigned short* whh1b = (unsigned short*)take((size_t)kG * kH * 2);
    unsigned short* wih2b = (unsigned short*)take((size_t)kG * kH * 2);
    unsigned short* whh2b = (unsigned short*)take((size_t)kG * kH * 2);
    unsigned short* wih1b = (unsigned short*)take((size_t)kG * 32 * 2);
    unsigned short* xb    = (unsigned short*)take((size_t)kSeq * kBatch * 32 * 2);
    char* state = p;
    unsigned short* h1r = (unsigned short*)take((size_t)kRing * kHSlot * 2);
    unsigned short* h2r = (unsigned short*)take((size_t)kRing * kHSlot * 2);
    int* flags = (int*)take(16384);
    size_t state_bytes = (size_t)((char*)flags + 16384 - state);
    float* h2f = (float*)take((size_t)kBatch * kH * 4);

    hipMemsetAsync(state, 0, state_bytes, stream);

    int n = kG * kH;
    k_conv<<<(n + 255) / 256, 256, 0, stream>>>(Whh1, whh1b, n);
    k_conv<<<(n + 255) / 256, 256, 0, stream>>>(Wih2, wih2b, n);
    k_conv<<<(n + 255) / 256, 256, 0, stream>>>(Whh2, whh2b, n);
    k_conv_pad<<<(kG * 32 + 255) / 256, 256, 0, stream>>>(Wih1, wih1b, kG);
    k_conv_pad<<<(kSeq * kBatch * 32 + 255) / 256, 256, 0, stream>>>(x, xb, kSeq * kBatch);

    hipFuncSetAttribute((const void*)k_persist,
                        hipFuncAttributeMaxDynamicSharedMemorySize, (int)kShmemBytes);
    void* args[] = {&whh1b, &wih1b, &wih2b, &whh2b, &xb,
                    (void*)&bih1, (void*)&bhh1, (void*)&bih2, (void*)&bhh2,
                    &h1r, &h2r, &h2f, &flags};
    hipError_t e = hipLaunchCooperativeKernel((const void*)k_persist, dim3(256), dim3(320),
                                              args, (unsigned)kShmemBytes, stream);
    if (e != hipSuccess) {
        k_persist<<<256, 320, kShmemBytes, stream>>>(
            whh1b, wih1b, wih2b, whh2b, xb, bih1, bhh1, bih2, bhh2,
            h1r, h2r, h2f, flags);
    }

    k_head<<<kBatch, 64, 0, stream>>>(h2f, fc1w, fc1b, fcw, fcb, out);
}